// Round 14
// baseline (105.188 us; speedup 1.0000x reference)
//
#include <hip/hip_runtime.h>

#define N_NODES 40000
#define N_EDGES 640000
#define D 128
#define CAP 64                      // fixed per-node edge capacity (mean deg 16)
#define ES_CAP (N_NODES * CAP)
#define NTILES (N_NODES / 32)       // 1250

typedef __attribute__((ext_vector_type(8))) short short8;   // 8 bf16 = 4 VGPR
typedef __attribute__((ext_vector_type(4))) float f32x4;
typedef __attribute__((ext_vector_type(2))) float f32x2;

__device__ __forceinline__ unsigned short f2bf(float f) {
    unsigned u = __float_as_uint(f);
    unsigned r = u + 0x7FFF + ((u >> 16) & 1);   // round-to-nearest-even
    return (unsigned short)(r >> 16);
}

// ---------------- merged prep+fill ------------------------------------------
// grid 2500 x 256 = 640000 threads; cnt zeroed beforehand via hipMemsetAsync.
// Thread t: x->bf16 + x->fp8 (8 elems), edge t count+scatter, weight pack,
// fp8 sentinel-row zero. Conversion BW work overlaps the edge atomic latency.

__global__ __launch_bounds__(256) void prep_fill(
    const float* __restrict__ x, unsigned short* __restrict__ xb,
    unsigned char* __restrict__ xq, unsigned char* __restrict__ h1q,
    const float* __restrict__ Ws1, const float* __restrict__ Wn1,
    const float* __restrict__ Ws2, const float* __restrict__ Wn2,
    unsigned* __restrict__ Wp, int* __restrict__ cnt,
    const int* __restrict__ src, const int* __restrict__ dst,
    int* __restrict__ edge_src) {
    int t = blockIdx.x * 256 + threadIdx.x;

    // start the edge chain early (load dst -> atomic -> scatter)
    int d = dst[t];
    int s = src[t];

    // zero fp8 sentinel rows (row N_NODES); bf16 sentinel rows never read
    if (t < 32) {
        ((unsigned*)xq)[N_NODES * 32 + t] = 0;
        ((unsigned*)h1q)[N_NODES * 32 + t] = 0;
    }

    // fp32 -> bf16 + fp8 feature planes (8 elems/thread)
    {
        float4 a = ((const float4*)x)[t * 2];
        float4 b = ((const float4*)x)[t * 2 + 1];
        uint4 o;
        o.x = f2bf(a.x) | ((unsigned)f2bf(a.y) << 16);
        o.y = f2bf(a.z) | ((unsigned)f2bf(a.w) << 16);
        o.z = f2bf(b.x) | ((unsigned)f2bf(b.y) << 16);
        o.w = f2bf(b.z) | ((unsigned)f2bf(b.w) << 16);
        ((uint4*)xb)[t] = o;
        int p0 = __builtin_amdgcn_cvt_pk_fp8_f32(a.x, a.y, 0, 0);
        p0     = __builtin_amdgcn_cvt_pk_fp8_f32(a.z, a.w, p0, 1);
        int p1 = __builtin_amdgcn_cvt_pk_fp8_f32(b.x, b.y, 0, 0);
        p1     = __builtin_amdgcn_cvt_pk_fp8_f32(b.z, b.w, p1, 1);
        ((uint2*)xq)[t] = make_uint2((unsigned)p0, (unsigned)p1);
    }

    // edge count + scatter (cnt pre-zeroed by memset)
    {
        int p = atomicAdd(&cnt[d], 1);
        if (p < CAP) edge_src[d * CAP + p] = s;   // overflow-safe (never hit)
    }

    // weight pre-pack into MFMA B-fragment order (bf16):
    // element (((q*8+c)*64+l)*8 + j) = W[(q&3)*32 + (l>>4)*8 + j][c*16 + (l&15)]
    if (t < 32768) {
        int L   = t >> 14;
        int rem = t & 16383;
        int j2 = rem & 3;
        int l  = (rem >> 2) & 63;
        int c  = (rem >> 8) & 7;
        int q  = rem >> 11;
        const float* W = (L == 0) ? (q < 4 ? Ws1 : Wn1) : (q < 4 ? Ws2 : Wn2);
        int k0  = (q & 3) * 32 + (l >> 4) * 8 + 2 * j2;
        int col = c * 16 + (l & 15);
        float v0 = W[(size_t)k0 * D + col];
        float v1 = W[(size_t)(k0 + 1) * D + col];
        Wp[t] = f2bf(v0) | ((unsigned)f2bf(v1) << 16);
    }
}

// ---------------- fused layer: fp8 mean-agg into LDS + dual bf16 MFMA GEMM --
// block = 32 nodes, 512 threads (8 waves), grid 1250.
// phase A: lane-group g (16 lanes) owns node w*4+g; fp8 rows (128 B = 1 line
//          per edge); 8 edges/step = 2 broadcast int4 index loads + 8 row
//          gathers. Unwritten slots hold garbage -> indices CLAMPED to the
//          sentinel row (N_NODES, zeroed) in-register; padding is 8.
// phase B: wave w computes rows (w>>2)*16..+15, cols (w&3)*32..+31;
//          self operand from bf16 plane, neigh operand from LDS mean tile.
// phase C: stage acc to LDS, vectorized bias(+relu) epilogue; layer 1 also
//          emits the fp8 copy of h1 for layer 2's gather.

#define PADW 68   // dwords per mean row in LDS (64 data + 4 pad)

__global__ __launch_bounds__(512) void fused_layer(
    const unsigned short* __restrict__ A,     // bf16 plane [N_NODES+1][128]
    const unsigned char* __restrict__ Aq,     // fp8 plane  [N_NODES+1][128]
    const int* __restrict__ deg,              // true degrees (cnt)
    const int* __restrict__ edge_src,         // fixed-stride, tail = garbage
    const unsigned* __restrict__ Wp,          // 16384 uints, fragment order
    const float* __restrict__ bias,
    unsigned short* __restrict__ outb,        // bf16 out (layer 1) or nullptr
    unsigned char*  __restrict__ outq,        // fp8 out (layer 1) or nullptr
    float* __restrict__ outf,                 // f32 out (layer 2) or nullptr
    int do_relu) {
    __shared__ float sf[32 * 132];            // 16896 B; aliased as mean tile
    unsigned* meanL = (unsigned*)sf;          // [32][PADW]

    int tid = threadIdx.x;
    int w = tid >> 6, l = tid & 63;
    int blk = blockIdx.x;
    int grp = l >> 4, sub = l & 15;

    // ---- phase A: one node per 16-lane group, fp8 rows, clamped indices ----
    {
        int myn = blk * 32 + w * 4 + grp;
        int dgv = deg[myn];
        int base = myn * CAP;
        int pd = (dgv + 7) & ~7;
        if (pd > CAP) pd = CAP;               // replay-safety clamp
        const uint2* q8 = (const uint2*)Aq;   // 16 uint2 per 128 B row
        f32x2 ca = {0.f, 0.f}, cb = {0.f, 0.f}, cc = {0.f, 0.f}, cd = {0.f, 0.f};
        for (int s = 0; s < pd; s += 8) {
            int4 qa = *(const int4*)&edge_src[base + s];
            int4 qb = *(const int4*)&edge_src[base + s + 4];
            int i0 = (s + 0 < dgv) ? qa.x : N_NODES;
            int i1 = (s + 1 < dgv) ? qa.y : N_NODES;
            int i2 = (s + 2 < dgv) ? qa.z : N_NODES;
            int i3 = (s + 3 < dgv) ? qa.w : N_NODES;
            int i4 = (s + 4 < dgv) ? qb.x : N_NODES;
            int i5 = (s + 5 < dgv) ? qb.y : N_NODES;
            int i6 = (s + 6 < dgv) ? qb.z : N_NODES;
            int i7 = (s + 7 < dgv) ? qb.w : N_NODES;
            uint2 u0 = q8[(size_t)i0 * 16 + sub];
            uint2 u1 = q8[(size_t)i1 * 16 + sub];
            uint2 u2 = q8[(size_t)i2 * 16 + sub];
            uint2 u3 = q8[(size_t)i3 * 16 + sub];
            uint2 u4 = q8[(size_t)i4 * 16 + sub];
            uint2 u5 = q8[(size_t)i5 * 16 + sub];
            uint2 u6 = q8[(size_t)i6 * 16 + sub];
            uint2 u7 = q8[(size_t)i7 * 16 + sub];
            ca += __builtin_amdgcn_cvt_pk_f32_fp8((int)u0.x, 0);
            cb += __builtin_amdgcn_cvt_pk_f32_fp8((int)u0.x, 1);
            cc += __builtin_amdgcn_cvt_pk_f32_fp8((int)u0.y, 0);
            cd += __builtin_amdgcn_cvt_pk_f32_fp8((int)u0.y, 1);
            ca += __builtin_amdgcn_cvt_pk_f32_fp8((int)u1.x, 0);
            cb += __builtin_amdgcn_cvt_pk_f32_fp8((int)u1.x, 1);
            cc += __builtin_amdgcn_cvt_pk_f32_fp8((int)u1.y, 0);
            cd += __builtin_amdgcn_cvt_pk_f32_fp8((int)u1.y, 1);
            ca += __builtin_amdgcn_cvt_pk_f32_fp8((int)u2.x, 0);
            cb += __builtin_amdgcn_cvt_pk_f32_fp8((int)u2.x, 1);
            cc += __builtin_amdgcn_cvt_pk_f32_fp8((int)u2.y, 0);
            cd += __builtin_amdgcn_cvt_pk_f32_fp8((int)u2.y, 1);
            ca += __builtin_amdgcn_cvt_pk_f32_fp8((int)u3.x, 0);
            cb += __builtin_amdgcn_cvt_pk_f32_fp8((int)u3.x, 1);
            cc += __builtin_amdgcn_cvt_pk_f32_fp8((int)u3.y, 0);
            cd += __builtin_amdgcn_cvt_pk_f32_fp8((int)u3.y, 1);
            ca += __builtin_amdgcn_cvt_pk_f32_fp8((int)u4.x, 0);
            cb += __builtin_amdgcn_cvt_pk_f32_fp8((int)u4.x, 1);
            cc += __builtin_amdgcn_cvt_pk_f32_fp8((int)u4.y, 0);
            cd += __builtin_amdgcn_cvt_pk_f32_fp8((int)u4.y, 1);
            ca += __builtin_amdgcn_cvt_pk_f32_fp8((int)u5.x, 0);
            cb += __builtin_amdgcn_cvt_pk_f32_fp8((int)u5.x, 1);
            cc += __builtin_amdgcn_cvt_pk_f32_fp8((int)u5.y, 0);
            cd += __builtin_amdgcn_cvt_pk_f32_fp8((int)u5.y, 1);
            ca += __builtin_amdgcn_cvt_pk_f32_fp8((int)u6.x, 0);
            cb += __builtin_amdgcn_cvt_pk_f32_fp8((int)u6.x, 1);
            cc += __builtin_amdgcn_cvt_pk_f32_fp8((int)u6.y, 0);
            cd += __builtin_amdgcn_cvt_pk_f32_fp8((int)u6.y, 1);
            ca += __builtin_amdgcn_cvt_pk_f32_fp8((int)u7.x, 0);
            cb += __builtin_amdgcn_cvt_pk_f32_fp8((int)u7.x, 1);
            cc += __builtin_amdgcn_cvt_pk_f32_fp8((int)u7.y, 0);
            cd += __builtin_amdgcn_cvt_pk_f32_fp8((int)u7.y, 1);
        }
        float inv = dgv > 0 ? 1.0f / (float)dgv : 0.f;
        uint4 o;
        o.x = f2bf(ca.x * inv) | ((unsigned)f2bf(ca.y * inv) << 16);
        o.y = f2bf(cb.x * inv) | ((unsigned)f2bf(cb.y * inv) << 16);
        o.z = f2bf(cc.x * inv) | ((unsigned)f2bf(cc.y * inv) << 16);
        o.w = f2bf(cd.x * inv) | ((unsigned)f2bf(cd.y * inv) << 16);
        *(uint4*)&meanL[(w * 4 + grp) * PADW + sub * 4] = o;
    }

    // ---- phase B: dual GEMM ----
    int rlo = l & 15, khi = l >> 4;
    int row0g = blk * 32 + (w >> 2) * 16;
    const unsigned short* ar = A + (size_t)(row0g + rlo) * D + khi * 8;

    f32x4 acc[2] = {};
    // self half first: no LDS dependence -> runs before the barrier
    #pragma unroll
    for (int q = 0; q < 4; ++q) {
        short8 a = *(const short8*)(ar + q * 32);
        #pragma unroll
        for (int c = 0; c < 2; ++c) {
            int cg = (w & 3) * 2 + c;
            short8 b = *(const short8*)(Wp + ((q * 8 + cg) * 64 + l) * 4);
            acc[c] = __builtin_amdgcn_mfma_f32_16x16x32_bf16(a, b, acc[c], 0, 0, 0);
        }
    }
    __syncthreads();
    // neigh half from LDS mean tile
    int lr0 = (w >> 2) * 16 + rlo;
    #pragma unroll
    for (int q = 4; q < 8; ++q) {
        short8 a = *(const short8*)(meanL + lr0 * PADW + khi * 4 + (q & 3) * 16);
        #pragma unroll
        for (int c = 0; c < 2; ++c) {
            int cg = (w & 3) * 2 + c;
            short8 b = *(const short8*)(Wp + ((q * 8 + cg) * 64 + l) * 4);
            acc[c] = __builtin_amdgcn_mfma_f32_16x16x32_bf16(a, b, acc[c], 0, 0, 0);
        }
    }
    __syncthreads();   // all reads of meanL done before sf overwrite

    // ---- phase C: epilogue via LDS stage ----
    #pragma unroll
    for (int c = 0; c < 2; ++c) {
        int cg = (w & 3) * 2 + c;
        #pragma unroll
        for (int j = 0; j < 4; ++j)
            sf[((w >> 2) * 16 + khi * 4 + j) * 132 + cg * 16 + rlo] = acc[c][j];
    }
    __syncthreads();

    int row = tid >> 4, c0 = (tid & 15) * 8;
    const float* srow = &sf[row * 132 + c0];
    float4 u0 = *(const float4*)(srow + 0);
    float4 u1 = *(const float4*)(srow + 4);
    float4 b0 = *(const float4*)(bias + c0 + 0);
    float4 b1 = *(const float4*)(bias + c0 + 4);
    size_t grow = (size_t)blk * 32 + row;
    if (do_relu) {
        float f0 = fmaxf(u0.x + b0.x, 0.f), f1 = fmaxf(u0.y + b0.y, 0.f);
        float f2 = fmaxf(u0.z + b0.z, 0.f), f3 = fmaxf(u0.w + b0.w, 0.f);
        float f4 = fmaxf(u1.x + b1.x, 0.f), f5 = fmaxf(u1.y + b1.y, 0.f);
        float f6 = fmaxf(u1.z + b1.z, 0.f), f7 = fmaxf(u1.w + b1.w, 0.f);
        uint4 o;
        o.x = f2bf(f0) | ((unsigned)f2bf(f1) << 16);
        o.y = f2bf(f2) | ((unsigned)f2bf(f3) << 16);
        o.z = f2bf(f4) | ((unsigned)f2bf(f5) << 16);
        o.w = f2bf(f6) | ((unsigned)f2bf(f7) << 16);
        *(uint4*)(outb + grow * D + c0) = o;
        int pq0 = __builtin_amdgcn_cvt_pk_fp8_f32(f0, f1, 0, 0);
        pq0     = __builtin_amdgcn_cvt_pk_fp8_f32(f2, f3, pq0, 1);
        int pq1 = __builtin_amdgcn_cvt_pk_fp8_f32(f4, f5, 0, 0);
        pq1     = __builtin_amdgcn_cvt_pk_fp8_f32(f6, f7, pq1, 1);
        *(uint2*)(outq + grow * D + c0) = make_uint2((unsigned)pq0, (unsigned)pq1);
    } else {
        float4 o0 = {u0.x + b0.x, u0.y + b0.y, u0.z + b0.z, u0.w + b0.w};
        float4 o1 = {u1.x + b1.x, u1.y + b1.y, u1.z + b1.z, u1.w + b1.w};
        *(float4*)(outf + grow * D + c0 + 0) = o0;
        *(float4*)(outf + grow * D + c0 + 4) = o1;
    }
}

// ---------------- launch (4 dispatches incl. memset) ----------------

extern "C" void kernel_launch(void* const* d_in, const int* in_sizes, int n_in,
                              void* d_out, int out_size, void* d_ws, size_t ws_size,
                              hipStream_t stream) {
    const float* x       = (const float*)d_in[0];
    const int*   src     = (const int*)d_in[1];
    const int*   dst     = (const int*)d_in[2];
    const float* W_self1 = (const float*)d_in[3];
    const float* W_neigh1= (const float*)d_in[4];
    const float* b1      = (const float*)d_in[5];
    const float* W_self2 = (const float*)d_in[6];
    const float* W_neigh2= (const float*)d_in[7];
    const float* b2      = (const float*)d_in[8];
    float* out = (float*)d_out;

    char* ws = (char*)d_ws;
    size_t off_cnt  = 0;                        // 40000 int
    size_t off_es   = 160256;                   // ES_CAP int = 10,240,000 B
    size_t off_xb   = 10400512;                 // (40001)*128 bf16
    size_t off_h1b  = 20640768;                 // (40001)*128 bf16
    size_t off_wp   = 30881024;                 // 2*16384 uint
    size_t off_xq   = 31012096;                 // (40001)*128 fp8
    size_t off_h1q  = 36132224;                 // (40001)*128 fp8
    size_t total    = 41252352;
    if (ws_size < total) return;

    int* cnt       = (int*)(ws + off_cnt);
    int* edge_src  = (int*)(ws + off_es);
    unsigned short* xb   = (unsigned short*)(ws + off_xb);
    unsigned short* h1b  = (unsigned short*)(ws + off_h1b);
    unsigned* Wp         = (unsigned*)(ws + off_wp);
    unsigned char* xq    = (unsigned char*)(ws + off_xq);
    unsigned char* h1q   = (unsigned char*)(ws + off_h1q);

    hipMemsetAsync(cnt, 0, 160000, stream);
    prep_fill<<<2500, 256, 0, stream>>>(x, xb, xq, h1q,
                                        W_self1, W_neigh1, W_self2, W_neigh2,
                                        Wp, cnt, src, dst, edge_src);

    fused_layer<<<NTILES, 512, 0, stream>>>(xb, xq, cnt, edge_src,
                                            Wp, b1, h1b, h1q, nullptr, 1);
    fused_layer<<<NTILES, 512, 0, stream>>>(h1b, h1q, cnt, edge_src,
                                            Wp + 16384, b2, nullptr, nullptr,
                                            out, 0);
}

// Round 15
// 90.329 us; speedup vs baseline: 1.1645x; 1.1645x over previous
//
#include <hip/hip_runtime.h>

#define N_NODES 40000
#define N_EDGES 640000
#define D 128
#define CAP 64                      // fixed per-node edge capacity (mean deg 16)
#define ES_CAP (N_NODES * CAP)
#define NTILES (N_NODES / 32)       // 1250

typedef __attribute__((ext_vector_type(8))) short short8;   // 8 bf16 = 4 VGPR
typedef __attribute__((ext_vector_type(4))) float f32x4;
typedef __attribute__((ext_vector_type(2))) float f32x2;

__device__ __forceinline__ unsigned short f2bf(float f) {
    unsigned u = __float_as_uint(f);
    unsigned r = u + 0x7FFF + ((u >> 16) & 1);   // round-to-nearest-even
    return (unsigned short)(r >> 16);
}

// ---------------- prep: cnt zero, x->bf16 + x->fp8, weight pack, ------------
// ---------------- fp8 sentinel-row zero (NO edge sentinel fill) -------------
// grid 2500 x 256 = 640000 threads. No atomics; counting happens in
// fill_edges (next dispatch), so zeroing cnt here is race-free.
// NOTE (r14 lesson): keep streaming stores and random atomics in SEPARATE
// kernels — merging them into one wave poisoned write-combining (59 us).

__global__ __launch_bounds__(256) void prep(
    const float* __restrict__ x, unsigned short* __restrict__ xb,
    unsigned char* __restrict__ xq, unsigned char* __restrict__ h1q,
    const float* __restrict__ Ws1, const float* __restrict__ Wn1,
    const float* __restrict__ Ws2, const float* __restrict__ Wn2,
    unsigned* __restrict__ Wp, int* __restrict__ cnt) {
    int t = blockIdx.x * 256 + threadIdx.x;

    if (t < N_NODES) cnt[t] = 0;

    // zero fp8 sentinel rows (row N_NODES); bf16 sentinel rows are never read
    if (t < 32) {
        ((unsigned*)xq)[N_NODES * 32 + t] = 0;
        ((unsigned*)h1q)[N_NODES * 32 + t] = 0;
    }

    // fp32 -> bf16 + fp8 feature planes (8 elems/thread)
    {
        float4 a = ((const float4*)x)[t * 2];
        float4 b = ((const float4*)x)[t * 2 + 1];
        uint4 o;
        o.x = f2bf(a.x) | ((unsigned)f2bf(a.y) << 16);
        o.y = f2bf(a.z) | ((unsigned)f2bf(a.w) << 16);
        o.z = f2bf(b.x) | ((unsigned)f2bf(b.y) << 16);
        o.w = f2bf(b.z) | ((unsigned)f2bf(b.w) << 16);
        ((uint4*)xb)[t] = o;
        int p0 = __builtin_amdgcn_cvt_pk_fp8_f32(a.x, a.y, 0, 0);
        p0     = __builtin_amdgcn_cvt_pk_fp8_f32(a.z, a.w, p0, 1);
        int p1 = __builtin_amdgcn_cvt_pk_fp8_f32(b.x, b.y, 0, 0);
        p1     = __builtin_amdgcn_cvt_pk_fp8_f32(b.z, b.w, p1, 1);
        ((uint2*)xq)[t] = make_uint2((unsigned)p0, (unsigned)p1);
    }

    // weight pre-pack into MFMA B-fragment order (bf16):
    // element (((q*8+c)*64+l)*8 + j) = W[(q&3)*32 + (l>>4)*8 + j][c*16 + (l&15)]
    if (t < 32768) {
        int L   = t >> 14;
        int rem = t & 16383;
        int j2 = rem & 3;
        int l  = (rem >> 2) & 63;
        int c  = (rem >> 8) & 7;
        int q  = rem >> 11;
        const float* W = (L == 0) ? (q < 4 ? Ws1 : Wn1) : (q < 4 ? Ws2 : Wn2);
        int k0  = (q & 3) * 32 + (l >> 4) * 8 + 2 * j2;
        int col = c * 16 + (l & 15);
        float v0 = W[(size_t)k0 * D + col];
        float v1 = W[(size_t)(k0 + 1) * D + col];
        Wp[t] = f2bf(v0) | ((unsigned)f2bf(v1) << 16);
    }
}

// ---------------- single-pass CSR fill (fixed 64-slot segments) -------------

__global__ void fill_edges(const int* __restrict__ src, const int* __restrict__ dst,
                           int* __restrict__ cnt, int* __restrict__ edge_src) {
    int e = blockIdx.x * 256 + threadIdx.x;
    if (e < N_EDGES) {
        int d = dst[e];
        int p = atomicAdd(&cnt[d], 1);
        if (p < CAP) edge_src[d * CAP + p] = src[e];   // overflow-safe (never hit)
    }
}

// ---------------- fused layer: fp8 mean-agg into LDS + dual bf16 MFMA GEMM --
// block = 32 nodes, 512 threads (8 waves), grid 1250.
// phase A: lane-group g (16 lanes) owns node w*4+g; fp8 rows (128 B = 1 line
//          per edge); 8 edges/step = 2 broadcast int4 index loads + 8 row
//          gathers. Unwritten slots hold garbage -> indices CLAMPED to the
//          sentinel row (N_NODES, zeroed) in-register; padding is 8.
// phase B: wave w computes rows (w>>2)*16..+15, cols (w&3)*32..+31;
//          self operand from bf16 plane, neigh operand from LDS mean tile.
// phase C: stage acc to LDS, vectorized bias(+relu) epilogue; layer 1 also
//          emits the fp8 copy of h1 for layer 2's gather.

#define PADW 68   // dwords per mean row in LDS (64 data + 4 pad)

__global__ __launch_bounds__(512) void fused_layer(
    const unsigned short* __restrict__ A,     // bf16 plane [N_NODES+1][128]
    const unsigned char* __restrict__ Aq,     // fp8 plane  [N_NODES+1][128]
    const int* __restrict__ deg,              // true degrees (cnt)
    const int* __restrict__ edge_src,         // fixed-stride, tail = garbage
    const unsigned* __restrict__ Wp,          // 16384 uints, fragment order
    const float* __restrict__ bias,
    unsigned short* __restrict__ outb,        // bf16 out (layer 1) or nullptr
    unsigned char*  __restrict__ outq,        // fp8 out (layer 1) or nullptr
    float* __restrict__ outf,                 // f32 out (layer 2) or nullptr
    int do_relu) {
    __shared__ float sf[32 * 132];            // 16896 B; aliased as mean tile
    unsigned* meanL = (unsigned*)sf;          // [32][PADW]

    int tid = threadIdx.x;
    int w = tid >> 6, l = tid & 63;
    int blk = blockIdx.x;
    int grp = l >> 4, sub = l & 15;

    // ---- phase A: one node per 16-lane group, fp8 rows, clamped indices ----
    {
        int myn = blk * 32 + w * 4 + grp;
        int dgv = deg[myn];
        int base = myn * CAP;
        int pd = (dgv + 7) & ~7;
        if (pd > CAP) pd = CAP;               // replay-safety clamp
        const uint2* q8 = (const uint2*)Aq;   // 16 uint2 per 128 B row
        f32x2 ca = {0.f, 0.f}, cb = {0.f, 0.f}, cc = {0.f, 0.f}, cd = {0.f, 0.f};
        for (int s = 0; s < pd; s += 8) {
            int4 qa = *(const int4*)&edge_src[base + s];
            int4 qb = *(const int4*)&edge_src[base + s + 4];
            int i0 = (s + 0 < dgv) ? qa.x : N_NODES;
            int i1 = (s + 1 < dgv) ? qa.y : N_NODES;
            int i2 = (s + 2 < dgv) ? qa.z : N_NODES;
            int i3 = (s + 3 < dgv) ? qa.w : N_NODES;
            int i4 = (s + 4 < dgv) ? qb.x : N_NODES;
            int i5 = (s + 5 < dgv) ? qb.y : N_NODES;
            int i6 = (s + 6 < dgv) ? qb.z : N_NODES;
            int i7 = (s + 7 < dgv) ? qb.w : N_NODES;
            uint2 u0 = q8[(size_t)i0 * 16 + sub];
            uint2 u1 = q8[(size_t)i1 * 16 + sub];
            uint2 u2 = q8[(size_t)i2 * 16 + sub];
            uint2 u3 = q8[(size_t)i3 * 16 + sub];
            uint2 u4 = q8[(size_t)i4 * 16 + sub];
            uint2 u5 = q8[(size_t)i5 * 16 + sub];
            uint2 u6 = q8[(size_t)i6 * 16 + sub];
            uint2 u7 = q8[(size_t)i7 * 16 + sub];
            ca += __builtin_amdgcn_cvt_pk_f32_fp8((int)u0.x, 0);
            cb += __builtin_amdgcn_cvt_pk_f32_fp8((int)u0.x, 1);
            cc += __builtin_amdgcn_cvt_pk_f32_fp8((int)u0.y, 0);
            cd += __builtin_amdgcn_cvt_pk_f32_fp8((int)u0.y, 1);
            ca += __builtin_amdgcn_cvt_pk_f32_fp8((int)u1.x, 0);
            cb += __builtin_amdgcn_cvt_pk_f32_fp8((int)u1.x, 1);
            cc += __builtin_amdgcn_cvt_pk_f32_fp8((int)u1.y, 0);
            cd += __builtin_amdgcn_cvt_pk_f32_fp8((int)u1.y, 1);
            ca += __builtin_amdgcn_cvt_pk_f32_fp8((int)u2.x, 0);
            cb += __builtin_amdgcn_cvt_pk_f32_fp8((int)u2.x, 1);
            cc += __builtin_amdgcn_cvt_pk_f32_fp8((int)u2.y, 0);
            cd += __builtin_amdgcn_cvt_pk_f32_fp8((int)u2.y, 1);
            ca += __builtin_amdgcn_cvt_pk_f32_fp8((int)u3.x, 0);
            cb += __builtin_amdgcn_cvt_pk_f32_fp8((int)u3.x, 1);
            cc += __builtin_amdgcn_cvt_pk_f32_fp8((int)u3.y, 0);
            cd += __builtin_amdgcn_cvt_pk_f32_fp8((int)u3.y, 1);
            ca += __builtin_amdgcn_cvt_pk_f32_fp8((int)u4.x, 0);
            cb += __builtin_amdgcn_cvt_pk_f32_fp8((int)u4.x, 1);
            cc += __builtin_amdgcn_cvt_pk_f32_fp8((int)u4.y, 0);
            cd += __builtin_amdgcn_cvt_pk_f32_fp8((int)u4.y, 1);
            ca += __builtin_amdgcn_cvt_pk_f32_fp8((int)u5.x, 0);
            cb += __builtin_amdgcn_cvt_pk_f32_fp8((int)u5.x, 1);
            cc += __builtin_amdgcn_cvt_pk_f32_fp8((int)u5.y, 0);
            cd += __builtin_amdgcn_cvt_pk_f32_fp8((int)u5.y, 1);
            ca += __builtin_amdgcn_cvt_pk_f32_fp8((int)u6.x, 0);
            cb += __builtin_amdgcn_cvt_pk_f32_fp8((int)u6.x, 1);
            cc += __builtin_amdgcn_cvt_pk_f32_fp8((int)u6.y, 0);
            cd += __builtin_amdgcn_cvt_pk_f32_fp8((int)u6.y, 1);
            ca += __builtin_amdgcn_cvt_pk_f32_fp8((int)u7.x, 0);
            cb += __builtin_amdgcn_cvt_pk_f32_fp8((int)u7.x, 1);
            cc += __builtin_amdgcn_cvt_pk_f32_fp8((int)u7.y, 0);
            cd += __builtin_amdgcn_cvt_pk_f32_fp8((int)u7.y, 1);
        }
        float inv = dgv > 0 ? 1.0f / (float)dgv : 0.f;
        uint4 o;
        o.x = f2bf(ca.x * inv) | ((unsigned)f2bf(ca.y * inv) << 16);
        o.y = f2bf(cb.x * inv) | ((unsigned)f2bf(cb.y * inv) << 16);
        o.z = f2bf(cc.x * inv) | ((unsigned)f2bf(cc.y * inv) << 16);
        o.w = f2bf(cd.x * inv) | ((unsigned)f2bf(cd.y * inv) << 16);
        *(uint4*)&meanL[(w * 4 + grp) * PADW + sub * 4] = o;
    }

    // ---- phase B: dual GEMM ----
    int rlo = l & 15, khi = l >> 4;
    int row0g = blk * 32 + (w >> 2) * 16;
    const unsigned short* ar = A + (size_t)(row0g + rlo) * D + khi * 8;

    f32x4 acc[2] = {};
    // self half first: no LDS dependence -> runs before the barrier
    #pragma unroll
    for (int q = 0; q < 4; ++q) {
        short8 a = *(const short8*)(ar + q * 32);
        #pragma unroll
        for (int c = 0; c < 2; ++c) {
            int cg = (w & 3) * 2 + c;
            short8 b = *(const short8*)(Wp + ((q * 8 + cg) * 64 + l) * 4);
            acc[c] = __builtin_amdgcn_mfma_f32_16x16x32_bf16(a, b, acc[c], 0, 0, 0);
        }
    }
    __syncthreads();
    // neigh half from LDS mean tile
    int lr0 = (w >> 2) * 16 + rlo;
    #pragma unroll
    for (int q = 4; q < 8; ++q) {
        short8 a = *(const short8*)(meanL + lr0 * PADW + khi * 4 + (q & 3) * 16);
        #pragma unroll
        for (int c = 0; c < 2; ++c) {
            int cg = (w & 3) * 2 + c;
            short8 b = *(const short8*)(Wp + ((q * 8 + cg) * 64 + l) * 4);
            acc[c] = __builtin_amdgcn_mfma_f32_16x16x32_bf16(a, b, acc[c], 0, 0, 0);
        }
    }
    __syncthreads();   // all reads of meanL done before sf overwrite

    // ---- phase C: epilogue via LDS stage ----
    #pragma unroll
    for (int c = 0; c < 2; ++c) {
        int cg = (w & 3) * 2 + c;
        #pragma unroll
        for (int j = 0; j < 4; ++j)
            sf[((w >> 2) * 16 + khi * 4 + j) * 132 + cg * 16 + rlo] = acc[c][j];
    }
    __syncthreads();

    int row = tid >> 4, c0 = (tid & 15) * 8;
    const float* srow = &sf[row * 132 + c0];
    float4 u0 = *(const float4*)(srow + 0);
    float4 u1 = *(const float4*)(srow + 4);
    float4 b0 = *(const float4*)(bias + c0 + 0);
    float4 b1 = *(const float4*)(bias + c0 + 4);
    size_t grow = (size_t)blk * 32 + row;
    if (do_relu) {
        float f0 = fmaxf(u0.x + b0.x, 0.f), f1 = fmaxf(u0.y + b0.y, 0.f);
        float f2 = fmaxf(u0.z + b0.z, 0.f), f3 = fmaxf(u0.w + b0.w, 0.f);
        float f4 = fmaxf(u1.x + b1.x, 0.f), f5 = fmaxf(u1.y + b1.y, 0.f);
        float f6 = fmaxf(u1.z + b1.z, 0.f), f7 = fmaxf(u1.w + b1.w, 0.f);
        uint4 o;
        o.x = f2bf(f0) | ((unsigned)f2bf(f1) << 16);
        o.y = f2bf(f2) | ((unsigned)f2bf(f3) << 16);
        o.z = f2bf(f4) | ((unsigned)f2bf(f5) << 16);
        o.w = f2bf(f6) | ((unsigned)f2bf(f7) << 16);
        *(uint4*)(outb + grow * D + c0) = o;
        int pq0 = __builtin_amdgcn_cvt_pk_fp8_f32(f0, f1, 0, 0);
        pq0     = __builtin_amdgcn_cvt_pk_fp8_f32(f2, f3, pq0, 1);
        int pq1 = __builtin_amdgcn_cvt_pk_fp8_f32(f4, f5, 0, 0);
        pq1     = __builtin_amdgcn_cvt_pk_fp8_f32(f6, f7, pq1, 1);
        *(uint2*)(outq + grow * D + c0) = make_uint2((unsigned)pq0, (unsigned)pq1);
    } else {
        float4 o0 = {u0.x + b0.x, u0.y + b0.y, u0.z + b0.z, u0.w + b0.w};
        float4 o1 = {u1.x + b1.x, u1.y + b1.y, u1.z + b1.z, u1.w + b1.w};
        *(float4*)(outf + grow * D + c0 + 0) = o0;
        *(float4*)(outf + grow * D + c0 + 4) = o1;
    }
}

// ---------------- launch (4 dispatches) ----------------

extern "C" void kernel_launch(void* const* d_in, const int* in_sizes, int n_in,
                              void* d_out, int out_size, void* d_ws, size_t ws_size,
                              hipStream_t stream) {
    const float* x       = (const float*)d_in[0];
    const int*   src     = (const int*)d_in[1];
    const int*   dst     = (const int*)d_in[2];
    const float* W_self1 = (const float*)d_in[3];
    const float* W_neigh1= (const float*)d_in[4];
    const float* b1      = (const float*)d_in[5];
    const float* W_self2 = (const float*)d_in[6];
    const float* W_neigh2= (const float*)d_in[7];
    const float* b2      = (const float*)d_in[8];
    float* out = (float*)d_out;

    char* ws = (char*)d_ws;
    size_t off_cnt  = 0;                        // 40000 int
    size_t off_es   = 160256;                   // ES_CAP int = 10,240,000 B
    size_t off_xb   = 10400512;                 // (40001)*128 bf16
    size_t off_h1b  = 20640768;                 // (40001)*128 bf16
    size_t off_wp   = 30881024;                 // 2*16384 uint
    size_t off_xq   = 31012096;                 // (40001)*128 fp8
    size_t off_h1q  = 36132224;                 // (40001)*128 fp8
    size_t total    = 41252352;
    if (ws_size < total) return;

    int* cnt       = (int*)(ws + off_cnt);
    int* edge_src  = (int*)(ws + off_es);
    unsigned short* xb   = (unsigned short*)(ws + off_xb);
    unsigned short* h1b  = (unsigned short*)(ws + off_h1b);
    unsigned* Wp         = (unsigned*)(ws + off_wp);
    unsigned char* xq    = (unsigned char*)(ws + off_xq);
    unsigned char* h1q   = (unsigned char*)(ws + off_h1q);

    prep<<<2500, 256, 0, stream>>>(x, xb, xq, h1q,
                                   W_self1, W_neigh1, W_self2, W_neigh2,
                                   Wp, cnt);
    fill_edges<<<(N_EDGES + 255) / 256, 256, 0, stream>>>(src, dst, cnt, edge_src);

    fused_layer<<<NTILES, 512, 0, stream>>>(xb, xq, cnt, edge_src,
                                            Wp, b1, h1b, h1q, nullptr, 1);
    fused_layer<<<NTILES, 512, 0, stream>>>(h1b, h1q, cnt, edge_src,
                                            Wp + 16384, b2, nullptr, nullptr,
                                            out, 0);
}